// Round 3
// baseline (284.246 us; speedup 1.0000x reference)
//
#include <hip/hip_runtime.h>

// OctVolSynth: element-wise over 256^3 volume.
//   scaling = lut[label]; v = scaling*texture; v = (v==0) ? 1 : v;
//   out0 = parenchyma * v;  out1 = (label != 0) ? 1.0f : 0.0f
// Outputs concatenated flat: [final_volume (N), vessel_mask (N)] as float32.
//
// R1 post-mortem: 12-VGPR serialized body was latency-bound (2.4 TB/s, 30%).
// R2/R3: 4x float4 per thread (16 elems) with phase-separated loads for MLP;
// nontemporal stores so the 134 MB write stream doesn't evict the 201 MB
// input set from the 256 MB L3. R3 fixes compile: nontemporal builtin needs
// native clang ext_vector_type, not HIP_vector_type.

#define N_ELEMS (256 * 256 * 256)
#define LUT_SIZE 302
#define BLOCK 256
#define CHUNKS 4   // float4 chunks per thread -> 16 elems/thread

typedef float vfloat4 __attribute__((ext_vector_type(4)));
typedef int   vint4   __attribute__((ext_vector_type(4)));

__global__ __launch_bounds__(BLOCK) void octvolsynth_kernel(
    const int* __restrict__ labels,
    const float* __restrict__ parenchyma,
    const float* __restrict__ texture,
    const float* __restrict__ lut,
    float* __restrict__ out)
{
    __shared__ float s_lut[LUT_SIZE];
    const int t = threadIdx.x;
    for (int i = t; i < LUT_SIZE; i += BLOCK) s_lut[i] = lut[i];
    __syncthreads();

    // vec index base: each block covers BLOCK*CHUNKS float4's, coalesced per chunk
    const int base = blockIdx.x * (BLOCK * CHUNKS) + t;

    const vint4*   l4p = (const vint4*)labels;
    const vfloat4* p4p = (const vfloat4*)parenchyma;
    const vfloat4* x4p = (const vfloat4*)texture;

    // Phase 1: all label loads in flight
    vint4 l4[CHUNKS];
#pragma unroll
    for (int c = 0; c < CHUNKS; ++c) l4[c] = l4p[base + c * BLOCK];

    // Phase 2: all parenchyma/texture loads in flight
    vfloat4 p4[CHUNKS], x4[CHUNKS];
#pragma unroll
    for (int c = 0; c < CHUNKS; ++c) p4[c] = p4p[base + c * BLOCK];
#pragma unroll
    for (int c = 0; c < CHUNKS; ++c) x4[c] = x4p[base + c * BLOCK];

    // Phase 3: LDS gathers (dependent on l4 only)
    float s[CHUNKS][4];
#pragma unroll
    for (int c = 0; c < CHUNKS; ++c) {
        s[c][0] = s_lut[l4[c].x];
        s[c][1] = s_lut[l4[c].y];
        s[c][2] = s_lut[l4[c].z];
        s[c][3] = s_lut[l4[c].w];
    }

    // Phase 4: compute + nontemporal stores
#pragma unroll
    for (int c = 0; c < CHUNKS; ++c) {
        vfloat4 fv, mv;
        float v0 = s[c][0] * x4[c].x;
        float v1 = s[c][1] * x4[c].y;
        float v2 = s[c][2] * x4[c].z;
        float v3 = s[c][3] * x4[c].w;
        fv.x = p4[c].x * ((v0 == 0.0f) ? 1.0f : v0);
        fv.y = p4[c].y * ((v1 == 0.0f) ? 1.0f : v1);
        fv.z = p4[c].z * ((v2 == 0.0f) ? 1.0f : v2);
        fv.w = p4[c].w * ((v3 == 0.0f) ? 1.0f : v3);
        mv.x = (l4[c].x != 0) ? 1.0f : 0.0f;
        mv.y = (l4[c].y != 0) ? 1.0f : 0.0f;
        mv.z = (l4[c].z != 0) ? 1.0f : 0.0f;
        mv.w = (l4[c].w != 0) ? 1.0f : 0.0f;
        __builtin_nontemporal_store(fv, (vfloat4*)out + (base + c * BLOCK));
        __builtin_nontemporal_store(mv, (vfloat4*)(out + N_ELEMS) + (base + c * BLOCK));
    }
}

extern "C" void kernel_launch(void* const* d_in, const int* in_sizes, int n_in,
                              void* d_out, int out_size, void* d_ws, size_t ws_size,
                              hipStream_t stream) {
    const int*   labels     = (const int*)d_in[0];
    const float* parenchyma = (const float*)d_in[1];
    const float* texture    = (const float*)d_in[2];
    const float* lut        = (const float*)d_in[3];
    float* out = (float*)d_out;

    const int n_vec = N_ELEMS / 4;                 // 4,194,304 float4's
    const int grid  = n_vec / (BLOCK * CHUNKS);    // 4096 blocks, no tail
    octvolsynth_kernel<<<grid, BLOCK, 0, stream>>>(labels, parenchyma, texture, lut, out);
}

// Round 4
// 283.036 us; speedup vs baseline: 1.0043x; 1.0043x over previous
//
#include <hip/hip_runtime.h>

// OctVolSynth: element-wise over 256^3 volume.
//   scaling = lut[label]; v = scaling*texture; v = (v==0) ? 1 : v;
//   out0 = parenchyma * v;  out1 = (label != 0) ? 1.0f : 0.0f
// Outputs concatenated flat: [final_volume (N), vessel_mask (N)] as float32.
//
// R1: one-shot 12-VGPR kernel, 98 us, 2.4 TB/s — latency-bound.
// R3: one-shot 4x-unrolled, 108 us — compiler re-serialized (VGPR=32); one-shot
//     waves never overlap their load chains (retire interval ~= full chain).
// R4: PERSISTENT grid-stride kernel, m13-copy-style: 2048 blocks x 256 = 8192
//     waves = 32/CU (entire grid co-resident, zero WG churn), 8 iterations per
//     thread, software-pipelined prefetch of next iteration's 3 loads before
//     processing current. LUT-in-LDS amortized 8x per wave.

#define N_ELEMS (256 * 256 * 256)
#define N_VEC   (N_ELEMS / 4)      // 4,194,304 float4's
#define LUT_SIZE 302
#define BLOCK 256
#define GRID 2048
#define STRIDE (BLOCK * GRID)      // 524,288 threads
#define ITERS (N_VEC / STRIDE)     // 8, exact (no tail)

typedef float vfloat4 __attribute__((ext_vector_type(4)));
typedef int   vint4   __attribute__((ext_vector_type(4)));

__global__ __launch_bounds__(BLOCK, 8) void octvolsynth_kernel(
    const int* __restrict__ labels,
    const float* __restrict__ parenchyma,
    const float* __restrict__ texture,
    const float* __restrict__ lut,
    float* __restrict__ out)
{
    __shared__ float s_lut[LUT_SIZE];
    const int t = threadIdx.x;
    for (int i = t; i < LUT_SIZE; i += BLOCK) s_lut[i] = lut[i];
    __syncthreads();

    const vint4*   l4p = (const vint4*)labels;
    const vfloat4* p4p = (const vfloat4*)parenchyma;
    const vfloat4* x4p = (const vfloat4*)texture;
    vfloat4* o0 = (vfloat4*)out;
    vfloat4* o1 = (vfloat4*)(out + N_ELEMS);

    int idx = blockIdx.x * BLOCK + t;

    // prologue: first iteration's loads in flight
    vint4   l = l4p[idx];
    vfloat4 p = p4p[idx];
    vfloat4 x = x4p[idx];

#pragma unroll
    for (int i = 0; i < ITERS; ++i) {
        const vint4   lc = l;
        const vfloat4 pc = p;
        const vfloat4 xc = x;
        const int cur = idx;
        idx += STRIDE;
        if (i + 1 < ITERS) {          // prefetch next iteration before using current
            l = l4p[idx];
            p = p4p[idx];
            x = x4p[idx];
        }

        float v0 = s_lut[lc.x] * xc.x;
        float v1 = s_lut[lc.y] * xc.y;
        float v2 = s_lut[lc.z] * xc.z;
        float v3 = s_lut[lc.w] * xc.w;

        vfloat4 fv, mv;
        fv.x = pc.x * ((v0 == 0.0f) ? 1.0f : v0);
        fv.y = pc.y * ((v1 == 0.0f) ? 1.0f : v1);
        fv.z = pc.z * ((v2 == 0.0f) ? 1.0f : v2);
        fv.w = pc.w * ((v3 == 0.0f) ? 1.0f : v3);
        mv.x = (lc.x != 0) ? 1.0f : 0.0f;
        mv.y = (lc.y != 0) ? 1.0f : 0.0f;
        mv.z = (lc.z != 0) ? 1.0f : 0.0f;
        mv.w = (lc.w != 0) ? 1.0f : 0.0f;

        __builtin_nontemporal_store(fv, o0 + cur);
        __builtin_nontemporal_store(mv, o1 + cur);
    }
}

extern "C" void kernel_launch(void* const* d_in, const int* in_sizes, int n_in,
                              void* d_out, int out_size, void* d_ws, size_t ws_size,
                              hipStream_t stream) {
    const int*   labels     = (const int*)d_in[0];
    const float* parenchyma = (const float*)d_in[1];
    const float* texture    = (const float*)d_in[2];
    const float* lut        = (const float*)d_in[3];
    float* out = (float*)d_out;

    octvolsynth_kernel<<<GRID, BLOCK, 0, stream>>>(labels, parenchyma, texture, lut, out);
}

// Round 5
// 277.398 us; speedup vs baseline: 1.0247x; 1.0203x over previous
//
#include <hip/hip_runtime.h>

// OctVolSynth: element-wise over 256^3 volume.
//   scaling = lut[label]; v = scaling*texture; v = (v==0) ? 1 : v;
//   out0 = parenchyma * v;  out1 = (label != 0) ? 1.0f : 0.0f
//
// R1 (serial, 12 VGPR): 98 us, 2.4 TB/s. R3 (phases): compiler sank loads,
// VGPR=32, 108 us. R4 (persistent+prefetch): compiler refused dbuf, VGPR=28,
// 107 us. Common failure: scheduler serializes to ~1 load in flight/wave.
// R5: pin the issue order with __builtin_amdgcn_sched_barrier(0) — all 12
// global loads (4x int4 + 4x float4 + 4x float4) must issue before any
// consumer. Plain stores (nt regressed). launch_bounds(256,4) allows the
// ~90 VGPRs needed to hold the load phase.

#define N_ELEMS (256 * 256 * 256)
#define LUT_SIZE 302
#define BLOCK 256
#define CHUNKS 4   // float4 chunks per thread -> 16 elems/thread

typedef float vfloat4 __attribute__((ext_vector_type(4)));
typedef int   vint4   __attribute__((ext_vector_type(4)));

__global__ __launch_bounds__(BLOCK, 4) void octvolsynth_kernel(
    const int* __restrict__ labels,
    const float* __restrict__ parenchyma,
    const float* __restrict__ texture,
    const float* __restrict__ lut,
    float* __restrict__ out)
{
    __shared__ float s_lut[LUT_SIZE];
    const int t = threadIdx.x;
    for (int i = t; i < LUT_SIZE; i += BLOCK) s_lut[i] = lut[i];
    __syncthreads();

    const int base = blockIdx.x * (BLOCK * CHUNKS) + t;

    const vint4*   l4p = (const vint4*)labels;
    const vfloat4* p4p = (const vfloat4*)parenchyma;
    const vfloat4* x4p = (const vfloat4*)texture;

    // ---- load phase: 12 independent global loads, all in flight ----
    vint4 l4[CHUNKS];
    vfloat4 p4[CHUNKS], x4[CHUNKS];
#pragma unroll
    for (int c = 0; c < CHUNKS; ++c) l4[c] = l4p[base + c * BLOCK];
#pragma unroll
    for (int c = 0; c < CHUNKS; ++c) p4[c] = p4p[base + c * BLOCK];
#pragma unroll
    for (int c = 0; c < CHUNKS; ++c) x4[c] = x4p[base + c * BLOCK];

    // forbid the scheduler from sinking any of the above loads below here
    __builtin_amdgcn_sched_barrier(0);

    // ---- consume phase: gather, compute, store ----
#pragma unroll
    for (int c = 0; c < CHUNKS; ++c) {
        float v0 = s_lut[l4[c].x] * x4[c].x;
        float v1 = s_lut[l4[c].y] * x4[c].y;
        float v2 = s_lut[l4[c].z] * x4[c].z;
        float v3 = s_lut[l4[c].w] * x4[c].w;

        vfloat4 fv, mv;
        fv.x = p4[c].x * ((v0 == 0.0f) ? 1.0f : v0);
        fv.y = p4[c].y * ((v1 == 0.0f) ? 1.0f : v1);
        fv.z = p4[c].z * ((v2 == 0.0f) ? 1.0f : v2);
        fv.w = p4[c].w * ((v3 == 0.0f) ? 1.0f : v3);
        mv.x = (l4[c].x != 0) ? 1.0f : 0.0f;
        mv.y = (l4[c].y != 0) ? 1.0f : 0.0f;
        mv.z = (l4[c].z != 0) ? 1.0f : 0.0f;
        mv.w = (l4[c].w != 0) ? 1.0f : 0.0f;

        ((vfloat4*)out)[base + c * BLOCK] = fv;
        ((vfloat4*)(out + N_ELEMS))[base + c * BLOCK] = mv;
    }
}

extern "C" void kernel_launch(void* const* d_in, const int* in_sizes, int n_in,
                              void* d_out, int out_size, void* d_ws, size_t ws_size,
                              hipStream_t stream) {
    const int*   labels     = (const int*)d_in[0];
    const float* parenchyma = (const float*)d_in[1];
    const float* texture    = (const float*)d_in[2];
    const float* lut        = (const float*)d_in[3];
    float* out = (float*)d_out;

    const int n_vec = N_ELEMS / 4;                 // 4,194,304 float4's
    const int grid  = n_vec / (BLOCK * CHUNKS);    // 4096 blocks, no tail
    octvolsynth_kernel<<<grid, BLOCK, 0, stream>>>(labels, parenchyma, texture, lut, out);
}